// Round 1
// baseline (63165.735 us; speedup 1.0000x reference)
//
#include <hip/hip_runtime.h>
#include <hip/hip_bf16.h>
#include <math.h>
#include <stdio.h>

// EncoDecLSTM: B=256, T=512, F=128, U=1024.
// R4: persistent cooperative segments. The R3 structure (1024 tiny dispatches,
// 1 block/CU, 2 waves/SIMD) spent ~80% of each 35us step on launch overhead +
// per-dispatch L2 invalidation (W re-fetched cold from LLC, 32 serial kc iters
// x ~700cy latency) rather than MFMA (~1.6us floor). This round:
//   (a) 32 LSTM steps per kernel via hipLaunchCooperativeKernel; inter-step
//       sync is a per-mb group barrier (4 independent groups of 64 blocks --
//       block (mb,ub) only touches h rows of its own mb). Producer fence =
//       __threadfence (wbl2) + release flag; consumers relaxed-spin + acquire.
//   (b) 1024-thread blocks: 16 waves/CU (4/SIMD) for 2x latency hiding. Each
//       wave owns ONE 16x16 gate tile (6 MFMA + 6 frag loads per kc).
// GEMM products/order and gate math are bit-identical to R3 -> absmax must
// reproduce 0.0078125 exactly.
// Numerics (unchanged from R3): fp32-equivalent recurrence via 3-limb bf16
// MFMA (hi/mid/lo = 24 mantissa bits; 6 limb products hh,hm,mh,mm,hl,lh with
// fp32 accumulate). Decoder identity: x_in == h, so z = h@(dec_Wx+dec_Wh)+b.
// Encoder folds x@Wx via K-concat (K=1152=36*32).

typedef __attribute__((ext_vector_type(8))) short short8;   // 8 x bf16
typedef __attribute__((ext_vector_type(4))) float f32x4;

#define MFMA(a, b, c) __builtin_amdgcn_mfma_f32_16x16x32_bf16(a, b, c, 0, 0, 0)

__device__ __forceinline__ short f2bf(float f) {
  union { __hip_bfloat16 h; short s; } u;
  u.h = __float2bfloat16(f);
  return u.s;
}
__device__ __forceinline__ void split3(float x, short& a, short& b, short& c) {
  union { __hip_bfloat16 h; short s; } u;
  u.h = __float2bfloat16(x); a = u.s;
  float r1 = x - __bfloat162float(u.h);
  u.h = __float2bfloat16(r1); b = u.s;
  float r2 = r1 - __bfloat162float(u.h);
  u.h = __float2bfloat16(r2); c = u.s;
}
__device__ __forceinline__ float sigm(float x) { return 1.0f / (1.0f + expf(-x)); }

// ---------------------------------------------------------------------------
// Pack weight matrix into B-fragment layout, 1 or 3 limbs.
// limbs==3: dst[((nt*KC+kc)*3+l)*64+lane][j] ; limbs==1: dst[(nt*KC+kc)*64+lane][j]
// holds B[k = kc*32 + (lane>>4)*8 + j][col]
// mode 0: dec combined (a+b), gate-grouped cols. mode 1: enc concat (k<1024 ->
// a=Wh else b=Wx[k-1024]), gate-grouped. mode 2/3: natural cols (ncols).
// gate-grouped: nt = ub*4+g -> col = g*1024 + ub*16 + (lane&15)
// ---------------------------------------------------------------------------
__global__ void pack_w(const float* __restrict__ a, const float* __restrict__ b,
                       short8* __restrict__ dst, int KC, int mode, int ncols,
                       int limbs) {
  int gid = blockIdx.x * 256 + threadIdx.x;
  int lane = gid & 63;
  int kc = (gid >> 6) % KC;
  int nt = gid / (KC * 64);
  int u16 = lane & 15, kq = lane >> 4;
  int kbase = kc * 32 + kq * 8;
  int col;
  if (mode <= 1) { int g = nt & 3, ub = nt >> 2; col = g * 1024 + ub * 16 + u16; }
  else col = nt * 16 + u16;
  short8 v0, v1, v2;
#pragma unroll
  for (int j = 0; j < 8; ++j) {
    int k = kbase + j;
    float x;
    if (mode == 0)      x = a[(size_t)k * 4096 + col] + b[(size_t)k * 4096 + col];
    else if (mode == 1) x = (k < 1024) ? a[(size_t)k * 4096 + col]
                                       : b[(size_t)(k - 1024) * 4096 + col];
    else                x = a[(size_t)k * ncols + col];
    short sa, sb, sc; split3(x, sa, sb, sc);
    v0[j] = sa; v1[j] = sb; v2[j] = sc;
  }
  if (limbs == 3) {
    size_t base = (size_t)(nt * KC + kc) * 3 * 64 + lane;
    dst[base] = v0; dst[base + 64] = v1; dst[base + 128] = v2;
  } else {
    dst[(size_t)(nt * KC + kc) * 64 + lane] = v0;
  }
}

// Pack 32 timesteps of input x into 3-limb A-fragment ring.
// dst[(((tloc*16+mt)*4+kx)*3+l)*64+lane][j] = x[b=mt*16+(lane&15)][t0+tloc][f=kx*32+(lane>>4)*8+j]
__global__ void pack_x32(const float* __restrict__ src, short8* __restrict__ dst,
                         int t0) {
  int gid = blockIdx.x * 256 + threadIdx.x;
  int lane = gid & 63;
  int kx = (gid >> 6) & 3;
  int mt = (gid >> 8) & 15;
  int tloc = gid >> 12;            // 0..31
  int bb = mt * 16 + (lane & 15);
  int fb = kx * 32 + (lane >> 4) * 8;
  const float* s = src + ((size_t)bb * 512 + (t0 + tloc)) * 128 + fb;
  short8 v0, v1, v2;
#pragma unroll
  for (int j = 0; j < 8; ++j) {
    short sa, sb, sc; split3(s[j], sa, sb, sc);
    v0[j] = sa; v1[j] = sb; v2[j] = sc;
  }
  size_t base = (size_t)((tloc * 16 + mt) * 4 + kx) * 3 * 64 + lane;
  dst[base] = v0; dst[base + 64] = v1; dst[base + 128] = v2;
}

__global__ void zero_f(float* p, int n) {
  int i = blockIdx.x * 256 + threadIdx.x;
  if (i < n) p[i] = 0.f;
}

// ---------------------------------------------------------------------------
// Persistent LSTM segment: nsteps timesteps in one cooperative kernel.
// 256 blocks x 1024 thr (16 waves = 4 wr x 4 wc; 4 waves/SIMD).
// Block owns 64 rows (mb) x 16 units (ub) -> 64 gate-cols; wave owns one
// 16x16 tile: rows mt=mb*4+wr, gate-cols nt=ub*4+wc.
// Per kc: 3 A-limb + 3 B-limb loads, 6 MFMA (limb products hh,hm,mh,mm,hl,lh).
// Inter-step sync: per-mb group barrier (64 blocks) -- block (mb,ub) reads h
// rows [mb*64,mb*64+64) only, which exactly the 64 blocks of group mb wrote.
// h double-buffers in Hb by step parity; c-state is block-private.
// ---------------------------------------------------------------------------
__global__ __launch_bounds__(1024) void lstm_seg(
    const short8* __restrict__ Ax, const short8* __restrict__ W,
    const float* __restrict__ bias, float* __restrict__ cst,
    short8* __restrict__ Hb, short8* __restrict__ Hring,
    int KC, int gstep, int nsteps, unsigned* __restrict__ bar) {
  int tid = threadIdx.x;
  int lane = tid & 63, wv = tid >> 6;
  int wr = wv & 3, wc = wv >> 2;                 // wc = gate 0..3
  int xcd = blockIdx.x & 7, idx = blockIdx.x >> 3;
  int mb = idx & 3, ub = xcd * 8 + (idx >> 2);   // ub in [0,64)
  int mt = mb * 4 + wr;                          // 16-row tile of A
  int nt = ub * 4 + wc;                          // gate-col tile of W
  int u16 = lane & 15, quad = lane >> 4;
  const size_t H3 = (size_t)16 * 32 * 3 * 64;    // short8 per 3-limb h-state
  const size_t XT = (size_t)16 * 4 * 3 * 64;     // short8 per 3-limb x step
  const size_t HR = (size_t)16 * 32 * 64;        // short8 per hi-limb h-state
  __shared__ float zt[64][68];                   // [row][gate*16+u], pad 68
  float bv = bias[wc * 1024 + ub * 16 + u16];
  unsigned* cnt = bar + mb;
  unsigned* gen = bar + 4 + mb;

  for (int i = 0; i < nsteps; ++i) {
    int t = gstep + i;
    const short8* Ah = Hb + (size_t)(t & 1) * H3;
    short8* Hnext = Hb + (size_t)((t + 1) & 1) * H3;
    const short8* Axs = Ax ? (Ax + (size_t)i * XT) : nullptr;
    const f32x4 z4 = {0.f, 0.f, 0.f, 0.f};
    f32x4 acc = z4;
    const short8* Bp = W + ((size_t)nt * KC) * 3 * 64 + lane;
    for (int kc = 0; kc < KC; ++kc) {
      const short8* Ap = (kc < 32)
          ? (Ah + ((size_t)(mt * 32 + kc) * 3) * 64 + lane)
          : (Axs + ((size_t)(mt * 4 + (kc - 32)) * 3) * 64 + lane);
      short8 a0 = Ap[0], a1 = Ap[64], a2 = Ap[128];
      short8 b0 = Bp[0], b1 = Bp[64], b2 = Bp[128];
      Bp += 192;
      // limb products: hh, hm, mh, mm, hl, lh  (residual ~2^-24) -- same
      // per-element accumulation order as R3 (bitwise-identical result)
      acc = MFMA(a0, b0, acc);
      acc = MFMA(a0, b1, acc);
      acc = MFMA(a1, b0, acc);
      acc = MFMA(a1, b1, acc);
      acc = MFMA(a0, b2, acc);
      acc = MFMA(a2, b0, acc);
    }

    // C/D layout: col = lane&15, row = quad*4 + reg   (m89/m91-verified)
#pragma unroll
    for (int r = 0; r < 4; ++r)
      zt[wr * 16 + quad * 4 + r][wc * 16 + u16] = acc[r] + bv;
    __syncthreads();

    if (tid < 128) {
      int r = tid >> 1, s = tid & 1;   // row 0..63, u-octet 0..1
      int m = mb * 64 + r;
      int ubase = ub * 16 + s * 8;
      float* cp = cst + (size_t)m * 1024 + ubase;
      short8 h0, h1, h2;
#pragma unroll
      for (int j = 0; j < 8; ++j) {
        int uu = s * 8 + j;
        float iv = zt[r][uu];
        float fv = zt[r][16 + uu];
        float gv = zt[r][32 + uu];
        float ov = zt[r][48 + uu];
        float cn = sigm(fv) * cp[j] + sigm(iv) * tanhf(gv);
        cp[j] = cn;
        float hval = sigm(ov) * tanhf(cn);
        short sa, sb, sc; split3(hval, sa, sb, sc);
        h0[j] = sa; h1[j] = sb; h2[j] = sc;
      }
      // emit h in 3-limb A-fragment layout for the next step's GEMM
      int mtw = m >> 4, r16 = m & 15;
      int kcw = ubase >> 5, ko = ubase & 31;
      int lane_t = r16 + 16 * (ko >> 3);
      size_t base = ((size_t)(mtw * 32 + kcw) * 3) * 64 + lane_t;
      Hnext[base] = h0; Hnext[base + 64] = h1; Hnext[base + 128] = h2;
      if (Hring)  // hi limb only, single-limb layout, for the projection
        Hring[(size_t)i * HR + (size_t)(mtw * 32 + kcw) * 64 + lane_t] = h0;
    }
    __syncthreads();   // all waves' h stores drained (vmcnt(0) before barrier)

    if (i + 1 < nsteps) {            // last step: kernel-end release suffices
      if (tid == 0) {
        __threadfence();             // wbl2+inv: publish h across XCDs
        unsigned tick = (unsigned)(t + 1);   // monotonic over the whole run
        unsigned old = __hip_atomic_fetch_add(cnt, 1u, __ATOMIC_ACQ_REL,
                                              __HIP_MEMORY_SCOPE_AGENT);
        if (old == 63u) {            // last of the 64-block mb-group
          __hip_atomic_store(cnt, 0u, __ATOMIC_RELAXED,
                             __HIP_MEMORY_SCOPE_AGENT);
          __hip_atomic_store(gen, tick, __ATOMIC_RELEASE,
                             __HIP_MEMORY_SCOPE_AGENT);
        } else {
          while (__hip_atomic_load(gen, __ATOMIC_RELAXED,
                                   __HIP_MEMORY_SCOPE_AGENT) < tick)
            __builtin_amdgcn_s_sleep(1);
        }
        __threadfence();             // acquire side: drop stale lines
      }
      __syncthreads();
    }
  }
}

// ---------------------------------------------------------------------------
// Fused projection: y = relu(hs @ d1W + b1) @ d2W + b2 over a 32-step chunk.
// 128 blocks x 256 thr; hs = hi-limb ring (single pass, bf16 error ~1e-3 ok).
// ---------------------------------------------------------------------------
__global__ __launch_bounds__(256) void proj(
    const short8* __restrict__ HS, const short8* __restrict__ W1,
    const float* __restrict__ b1, const short8* __restrict__ W2,
    const float* __restrict__ b2, float* __restrict__ out, int t0) {
  int tid = threadIdx.x;
  int lane = tid & 63, wv = tid >> 6;
  int wr = wv & 1, wc = wv >> 1;
  int tloc = blockIdx.x >> 2, mb = blockIdx.x & 3;
  int t = t0 + tloc;
  const short8* A = HS + (size_t)tloc * 16 * 32 * 64;
  int u16 = lane & 15, quad = lane >> 4;
  int mt0 = mb * 4 + wr * 2;
  __shared__ short a1f[4][8][512];   // A1 quarter in A-fragment layout, 32 KB
  const f32x4 z4 = {0.f, 0.f, 0.f, 0.f};
  f32x4 acc2[2][4];
#pragma unroll
  for (int i = 0; i < 2; ++i)
#pragma unroll
    for (int jj = 0; jj < 4; ++jj) acc2[i][jj] = z4;

  for (int q = 0; q < 4; ++q) {
    f32x4 acc1[2][8];
#pragma unroll
    for (int i = 0; i < 2; ++i)
#pragma unroll
      for (int n = 0; n < 8; ++n) acc1[i][n] = z4;
    for (int kc = 0; kc < 32; ++kc) {
      short8 av0 = A[(size_t)(mt0 * 32 + kc) * 64 + lane];
      short8 av1 = A[(size_t)((mt0 + 1) * 32 + kc) * 64 + lane];
#pragma unroll
      for (int n = 0; n < 8; ++n) {
        int nt = q * 16 + wc * 8 + n;
        short8 bv = W1[(size_t)(nt * 32 + kc) * 64 + lane];
        acc1[0][n] = MFMA(av0, bv, acc1[0][n]);
        acc1[1][n] = MFMA(av1, bv, acc1[1][n]);
      }
    }
    __syncthreads();   // previous quarter's GEMM2 reads are done
#pragma unroll
    for (int i = 0; i < 2; ++i)
#pragma unroll
      for (int n = 0; n < 8; ++n)
#pragma unroll
        for (int r = 0; r < 4; ++r) {
          int rl = wr * 32 + i * 16 + quad * 4 + r;
          int nloc = wc * 128 + n * 16 + u16;
          float v = fmaxf(acc1[i][n][r] + b1[q * 256 + nloc], 0.f);
          int mtl = rl >> 4, r16 = rl & 15;
          int kcl = nloc >> 5, ko = nloc & 31;
          a1f[mtl][kcl][(r16 + 16 * (ko >> 3)) * 8 + (ko & 7)] = f2bf(v);
        }
    __syncthreads();
    for (int kcl = 0; kcl < 8; ++kcl) {
      short8 av0 = *(const short8*)&a1f[wr * 2 + 0][kcl][lane * 8];
      short8 av1 = *(const short8*)&a1f[wr * 2 + 1][kcl][lane * 8];
#pragma unroll
      for (int jj = 0; jj < 4; ++jj) {
        int nt2 = wc * 4 + jj;
        short8 bv = W2[(size_t)(nt2 * 32 + q * 8 + kcl) * 64 + lane];
        acc2[0][jj] = MFMA(av0, bv, acc2[0][jj]);
        acc2[1][jj] = MFMA(av1, bv, acc2[1][jj]);
      }
    }
  }
#pragma unroll
  for (int i = 0; i < 2; ++i)
#pragma unroll
    for (int jj = 0; jj < 4; ++jj)
#pragma unroll
      for (int r = 0; r < 4; ++r) {
        int rl = wr * 32 + i * 16 + quad * 4 + r;
        int f = wc * 64 + jj * 16 + u16;
        int bb = mb * 64 + rl;
        out[((size_t)bb * 512 + t) * 128 + f] = acc2[i][jj][r] + b2[f];
      }
}

extern "C" void kernel_launch(void* const* d_in, const int* in_sizes, int n_in,
                              void* d_out, int out_size, void* d_ws, size_t ws_size,
                              hipStream_t stream) {
  const float* x     = (const float*)d_in[0];
  const float* encWx = (const float*)d_in[1];
  const float* encWh = (const float*)d_in[2];
  const float* encb  = (const float*)d_in[3];
  const float* decWx = (const float*)d_in[4];
  const float* decWh = (const float*)d_in[5];
  const float* decb  = (const float*)d_in[6];
  const float* d1W   = (const float*)d_in[7];
  const float* d1b   = (const float*)d_in[8];
  const float* d2W   = (const float*)d_in[9];
  const float* d2b   = (const float*)d_in[10];

  char* ws = (char*)d_ws;
  size_t off = 0;
  short8* Wenc = (short8*)(ws + off); off += (size_t)256 * 36 * 3 * 64 * 16;  // 28.3 MB
  short8* Wdec = (short8*)(ws + off); off += (size_t)256 * 32 * 3 * 64 * 16;  // 25.2 MB
  short8* W1   = (short8*)(ws + off); off += (size_t)64 * 32 * 64 * 16;       //  2.10 MB
  short8* W2   = (short8*)(ws + off); off += (size_t)8 * 32 * 64 * 16;        //  0.26 MB
  short8* Xr   = (short8*)(ws + off); off += (size_t)32 * 16 * 4 * 3 * 64 * 16;   //  6.29 MB
  short8* Hb   = (short8*)(ws + off); off += (size_t)2 * 16 * 32 * 3 * 64 * 16;   //  3.15 MB
  short8* Hring= (short8*)(ws + off); off += (size_t)32 * 16 * 32 * 64 * 16;      // 16.78 MB
  float*  cst  = (float*)(ws + off);  off += (size_t)256 * 1024 * 4;              //  1.05 MB
  unsigned* bar = (unsigned*)(ws + off); off += 256;  // cnt[4] + gen[4]
  (void)in_sizes; (void)n_in; (void)out_size;  // total ~83.1 MB
  if (ws_size < off) {
    fprintf(stderr, "kernel_launch: ws_size=%zu < needed=%zu -- aborting launch\n",
            ws_size, off);
    return;
  }

  pack_w<<<2304, 256, 0, stream>>>(encWh, encWx, Wenc, 36, 1, 4096, 3);
  pack_w<<<2048, 256, 0, stream>>>(decWx, decWh, Wdec, 32, 0, 4096, 3);
  pack_w<<<512, 256, 0, stream>>>(d1W, nullptr, W1, 32, 2, 1024, 1);
  pack_w<<<64, 256, 0, stream>>>(d2W, nullptr, W2, 32, 3, 128, 1);
  zero_f<<<1536, 256, 0, stream>>>((float*)Hb, 16 * 32 * 3 * 64 * 8);  // h0 = 0 (buf 0)
  zero_f<<<1024, 256, 0, stream>>>(cst, 256 * 1024);                   // c0 = 0
  zero_f<<<1, 256, 0, stream>>>((float*)bar, 8);                       // barrier state

  for (int c = 0; c < 16; ++c) {                // encoder, 16 chunks x 32 steps
    pack_x32<<<512, 256, 0, stream>>>(x, Xr, c * 32);
    const short8* axp = Xr; const short8* wp = Wenc; const float* bp = encb;
    float* cp = cst; short8* hbp = Hb; short8* hrp = nullptr;
    int kcv = 36, gs = c * 32, ns = 32; unsigned* barp = bar;
    void* args[] = {&axp, &wp, &bp, &cp, &hbp, &hrp, &kcv, &gs, &ns, &barp};
    hipError_t e = hipLaunchCooperativeKernel((const void*)lstm_seg, dim3(256),
                                              dim3(1024), args, 0, stream);
    if (e != hipSuccess) {
      fprintf(stderr, "coop launch failed (enc c=%d): %s\n", c, hipGetErrorString(e));
      return;
    }
  }
  // final encoder h sits in Hb buffer 0 (parity of t=512)
  for (int c = 0; c < 16; ++c) {                // decoder, 16 chunks x 32 steps
    const short8* axp = nullptr; const short8* wp = Wdec; const float* bp = decb;
    float* cp = cst; short8* hbp = Hb; short8* hrp = Hring;
    int kcv = 32, gs = 512 + c * 32, ns = 32; unsigned* barp = bar;
    void* args[] = {&axp, &wp, &bp, &cp, &hbp, &hrp, &kcv, &gs, &ns, &barp};
    hipError_t e = hipLaunchCooperativeKernel((const void*)lstm_seg, dim3(256),
                                              dim3(1024), args, 0, stream);
    if (e != hipSuccess) {
      fprintf(stderr, "coop launch failed (dec c=%d): %s\n", c, hipGetErrorString(e));
      return;
    }
    proj<<<128, 256, 0, stream>>>(Hring, W1, d1b, W2, d2b, (float*)d_out, c * 32);
  }
}

// Round 2
// 45381.528 us; speedup vs baseline: 1.3919x; 1.3919x over previous
//
#include <hip/hip_runtime.h>
#include <hip/hip_bf16.h>
#include <math.h>
#include <stdio.h>

// EncoDecLSTM: B=256, T=512, F=128, U=1024.
// R5: persistent segments WITHOUT acquire fences. R4's 63us/step was
// FETCH-bound: ACQ fences emitted buffer_inv every step -> whole W (20.7MB)
// re-fetched from LLC per step at 379GB/s effective (= the step time), with
// zero prefetch depth (VGPR=28). This round:
//  (a) RELEASE-only publication + 9-slot fresh-address h ring (slot = t%9,
//      8-step segments): consumer never re-reads an address within a segment
//      -> no stale-line hazard -> no buffer_inv needed -> W stays hot in L2.
//  (b) 512-thr blocks, wave tile 32rx16c (2 accs): A reg-staged into LDS
//      (3-buffer rotation, loads issued 2 kc-pairs ahead to hide LLC), B
//      register-direct from L2-resident W. One raw s_barrier + lgkmcnt(0)
//      per kc-pair. Gate tail parallelized to all 512 threads (LDS bounce).
// GEMM product order and gate math bit-identical to R3/R4 -> absmax must
// reproduce 0.0078125 exactly.
// Numerics: fp32-equivalent recurrence via 3-limb bf16 MFMA (hi/mid/lo = 24
// mantissa bits; 6 limb products hh,hm,mh,mm,hl,lh, fp32 accumulate).
// Decoder identity: x_in == h, so z = h@(dec_Wx+dec_Wh)+b. Encoder folds
// x@Wx via K-concat (K=1152=36*32).

typedef __attribute__((ext_vector_type(8))) short short8;   // 8 x bf16
typedef __attribute__((ext_vector_type(4))) float f32x4;

#define MFMA(a, b, c) __builtin_amdgcn_mfma_f32_16x16x32_bf16(a, b, c, 0, 0, 0)

#define SEG_STEPS 8
#define RING_SLOTS 9   // SEG_STEPS+1: reads within a segment hit distinct slots

__device__ __forceinline__ short f2bf(float f) {
  union { __hip_bfloat16 h; short s; } u;
  u.h = __float2bfloat16(f);
  return u.s;
}
__device__ __forceinline__ void split3(float x, short& a, short& b, short& c) {
  union { __hip_bfloat16 h; short s; } u;
  u.h = __float2bfloat16(x); a = u.s;
  float r1 = x - __bfloat162float(u.h);
  u.h = __float2bfloat16(r1); b = u.s;
  float r2 = r1 - __bfloat162float(u.h);
  u.h = __float2bfloat16(r2); c = u.s;
}
__device__ __forceinline__ float sigm(float x) { return 1.0f / (1.0f + expf(-x)); }

// ---------------------------------------------------------------------------
// Pack weight matrix into B-fragment layout, 1 or 3 limbs.
// limbs==3: dst[((nt*KC+kc)*3+l)*64+lane][j] ; limbs==1: dst[(nt*KC+kc)*64+lane][j]
// holds B[k = kc*32 + (lane>>4)*8 + j][col]
// mode 0: dec combined (a+b), gate-grouped cols. mode 1: enc concat (k<1024 ->
// a=Wh else b=Wx[k-1024]), gate-grouped. mode 2/3: natural cols (ncols).
// gate-grouped: nt = ub*4+g -> col = g*1024 + ub*16 + (lane&15)
// ---------------------------------------------------------------------------
__global__ void pack_w(const float* __restrict__ a, const float* __restrict__ b,
                       short8* __restrict__ dst, int KC, int mode, int ncols,
                       int limbs) {
  int gid = blockIdx.x * 256 + threadIdx.x;
  int lane = gid & 63;
  int kc = (gid >> 6) % KC;
  int nt = gid / (KC * 64);
  int u16 = lane & 15, kq = lane >> 4;
  int kbase = kc * 32 + kq * 8;
  int col;
  if (mode <= 1) { int g = nt & 3, ub = nt >> 2; col = g * 1024 + ub * 16 + u16; }
  else col = nt * 16 + u16;
  short8 v0, v1, v2;
#pragma unroll
  for (int j = 0; j < 8; ++j) {
    int k = kbase + j;
    float x;
    if (mode == 0)      x = a[(size_t)k * 4096 + col] + b[(size_t)k * 4096 + col];
    else if (mode == 1) x = (k < 1024) ? a[(size_t)k * 4096 + col]
                                       : b[(size_t)(k - 1024) * 4096 + col];
    else                x = a[(size_t)k * ncols + col];
    short sa, sb, sc; split3(x, sa, sb, sc);
    v0[j] = sa; v1[j] = sb; v2[j] = sc;
  }
  if (limbs == 3) {
    size_t base = (size_t)(nt * KC + kc) * 3 * 64 + lane;
    dst[base] = v0; dst[base + 64] = v1; dst[base + 128] = v2;
  } else {
    dst[(size_t)(nt * KC + kc) * 64 + lane] = v0;
  }
}

// Pack 32 timesteps of input x into 3-limb A-fragment ring.
// dst[(((tloc*16+mt)*4+kx)*3+l)*64+lane][j] = x[b=mt*16+(lane&15)][t0+tloc][f=kx*32+(lane>>4)*8+j]
__global__ void pack_x32(const float* __restrict__ src, short8* __restrict__ dst,
                         int t0) {
  int gid = blockIdx.x * 256 + threadIdx.x;
  int lane = gid & 63;
  int kx = (gid >> 6) & 3;
  int mt = (gid >> 8) & 15;
  int tloc = gid >> 12;            // 0..31
  int bb = mt * 16 + (lane & 15);
  int fb = kx * 32 + (lane >> 4) * 8;
  const float* s = src + ((size_t)bb * 512 + (t0 + tloc)) * 128 + fb;
  short8 v0, v1, v2;
#pragma unroll
  for (int j = 0; j < 8; ++j) {
    short sa, sb, sc; split3(s[j], sa, sb, sc);
    v0[j] = sa; v1[j] = sb; v2[j] = sc;
  }
  size_t base = (size_t)((tloc * 16 + mt) * 4 + kx) * 3 * 64 + lane;
  dst[base] = v0; dst[base + 64] = v1; dst[base + 128] = v2;
}

__global__ void zero_f(float* p, int n) {
  int i = blockIdx.x * 256 + threadIdx.x;
  if (i < n) p[i] = 0.f;
}

// ---------------------------------------------------------------------------
// Persistent LSTM segment: SEG_STEPS timesteps per launch.
// 256 blocks x 512 thr (8 waves). Block owns 64 rows (mb) x 16 units (ub).
// Wave tile: 32 rows x 16 gate-cols: wr = wv&1 (mt pair), wc = wv>>1 (gate).
// Per kc-pair j (2 kc): A(j+1) ds_written from regs loaded at j-1 (LLC latency
// hidden across 2 iterations); B (3 limbs/kc) register-direct from L2-hot W;
// 12 ds_read_b128 + 24 MFMA; one raw s_barrier + lgkmcnt(0).
// 3-buffer LDS rotation: [W(j+1); load A(j+2); lgkm0; BAR; R(j)] is race-free.
// Inter-step sync: per-mb group of 64 blocks, RELEASE-only atomics (wbl2, no
// inv) + monotonic generation ticks; consumers spin RELAXED. h ring slot =
// t % RING_SLOTS -> fresh addresses, no stale-L2 hazard without acquire.
// ---------------------------------------------------------------------------
template<int KCT>
__global__ __launch_bounds__(512) void lstm_seg(
    const short8* __restrict__ Ax, const short8* __restrict__ W,
    const float* __restrict__ bias, float* __restrict__ cst,
    short8* __restrict__ ring, short8* __restrict__ Hring,
    int gstep, unsigned* __restrict__ bar) {
  constexpr int NJ = KCT / 2;
  int tid = threadIdx.x;
  int lane = tid & 63, wv = tid >> 6;
  int wr = wv & 1, wc = wv >> 1;                 // compute tile: rows 2wr..2wr+1 (mt-local), gate wc
  int wkcin = wv >> 2, wmtl = wv & 3;            // staging role: kc-in-pair, mt-local
  int xcd = blockIdx.x & 7, idx = blockIdx.x >> 3;
  int mb = idx & 3, ub = xcd * 8 + (idx >> 2);   // ub in [0,64)
  int u16 = lane & 15, quad = lane >> 4;
  const size_t H3R = (size_t)16 * 32 * 3 * 64;   // short8 per ring slot
  const size_t XT  = (size_t)16 * 4 * 3 * 64;    // short8 per 3-limb x step
  const size_t HR  = (size_t)16 * 32 * 64;       // short8 per hi-limb h-state
  __shared__ short8 stg[3][2][4][3][64];         // 72 KB: [buf][kcin][mtl][limb][lane]
  __shared__ float zt[64][68];                   // 17.4 KB, [row][gate*16+u]
  __shared__ __align__(16) short hb[64][48];     // 6 KB, [row][limb*16+u]
  float bv = bias[wc * 1024 + ub * 16 + u16];
  unsigned* cnt = bar + mb;
  unsigned* gen = bar + 4 + mb;
  int smt = mb * 4 + wmtl;                       // staging mt (global)

  for (int i = 0; i < SEG_STEPS; ++i) {
    int t = gstep + i;
    const short8* slotR = ring + (size_t)(t % RING_SLOTS) * H3R;
    short8* slotW = ring + (size_t)((t + 1) % RING_SLOTS) * H3R;
    const short8* Axs = (KCT == 36) ? (Ax + (size_t)(t & 31) * XT) : nullptr;
    // staging source for column-chunk kc (this wave's mt, +lane folded in)
    auto asrc = [&](int kc) -> const short8* {
      if (KCT == 36 && kc >= 32)
        return Axs + ((size_t)(smt * 4 + (kc - 32)) * 3) * 64 + lane;
      return slotR + ((size_t)(smt * 32 + kc) * 3) * 64 + lane;
    };
    // prologue: stage j=0 directly; preload regs for j=1
    {
      const short8* p = asrc(wkcin);
      short8 w0 = p[0], w1 = p[64], w2 = p[128];
      short8* d = &stg[0][wkcin][wmtl][0][lane];
      d[0] = w0; d[64] = w1; d[128] = w2;
    }
    short8 rA0, rA1, rA2;
    { const short8* p = asrc(2 + wkcin); rA0 = p[0]; rA1 = p[64]; rA2 = p[128]; }
    const f32x4 z4 = {0.f, 0.f, 0.f, 0.f};
    f32x4 acc0 = z4, acc1 = z4;
    const short8* Bp = W + ((size_t)(ub * 4 + wc) * KCT) * 3 * 64 + lane;
    asm volatile("s_waitcnt lgkmcnt(0)" ::: "memory");
    __builtin_amdgcn_s_barrier();
    asm volatile("" ::: "memory");
    int bsel = 0;
    for (int j = 0; j < NJ; ++j) {
      int bnext = bsel + 1; if (bnext == 3) bnext = 0;
      if (j + 1 < NJ) {                 // ds_write A(j+1) from regs
        short8* d = &stg[bnext][wkcin][wmtl][0][lane];
        d[0] = rA0; d[64] = rA1; d[128] = rA2;
      }
      if (j + 2 < NJ) {                 // issue global loads for A(j+2)
        const short8* p = asrc(2 * (j + 2) + wkcin);
        rA0 = p[0]; rA1 = p[64]; rA2 = p[128];
      }
      asm volatile("s_waitcnt lgkmcnt(0)" ::: "memory");
      __builtin_amdgcn_s_barrier();
      asm volatile("" ::: "memory");
#pragma unroll
      for (int kcin = 0; kcin < 2; ++kcin) {
        short8 b0 = Bp[0], b1 = Bp[64], b2 = Bp[128];
        Bp += 192;
        short8 x0 = stg[bsel][kcin][2 * wr + 0][0][lane];
        short8 x1 = stg[bsel][kcin][2 * wr + 0][1][lane];
        short8 x2 = stg[bsel][kcin][2 * wr + 0][2][lane];
        short8 y0 = stg[bsel][kcin][2 * wr + 1][0][lane];
        short8 y1 = stg[bsel][kcin][2 * wr + 1][1][lane];
        short8 y2 = stg[bsel][kcin][2 * wr + 1][2][lane];
        // limb products hh,hm,mh,mm,hl,lh -- same per-acc order as R3/R4
        acc0 = MFMA(x0, b0, acc0);  acc1 = MFMA(y0, b0, acc1);
        acc0 = MFMA(x0, b1, acc0);  acc1 = MFMA(y0, b1, acc1);
        acc0 = MFMA(x1, b0, acc0);  acc1 = MFMA(y1, b0, acc1);
        acc0 = MFMA(x1, b1, acc0);  acc1 = MFMA(y1, b1, acc1);
        acc0 = MFMA(x0, b2, acc0);  acc1 = MFMA(y0, b2, acc1);
        acc0 = MFMA(x2, b0, acc0);  acc1 = MFMA(y2, b0, acc1);
      }
      bsel = bnext;
    }

    // C/D layout: col = lane&15, row = quad*4 + reg   (m89/m91-verified)
#pragma unroll
    for (int r = 0; r < 4; ++r) {
      zt[(2 * wr + 0) * 16 + quad * 4 + r][wc * 16 + u16] = acc0[r] + bv;
      zt[(2 * wr + 1) * 16 + quad * 4 + r][wc * 16 + u16] = acc1[r] + bv;
    }
    __syncthreads();

    // gates: all 512 threads, 2 units each (bit-identical math)
    {
      int r = tid >> 3, up = tid & 7;
      int m = mb * 64 + r;
      float2* cp2 = (float2*)(cst + (size_t)m * 1024 + ub * 16) + up;
      float2 cv = *cp2;
#pragma unroll
      for (int jj = 0; jj < 2; ++jj) {
        int uu = up * 2 + jj;
        float iv = zt[r][uu];
        float fv = zt[r][16 + uu];
        float gv = zt[r][32 + uu];
        float ov = zt[r][48 + uu];
        float cin = jj ? cv.y : cv.x;
        float cn = sigm(fv) * cin + sigm(iv) * tanhf(gv);
        if (jj) cv.y = cn; else cv.x = cn;
        float hval = sigm(ov) * tanhf(cn);
        short sa, sb, sc; split3(hval, sa, sb, sc);
        hb[r][uu] = sa; hb[r][16 + uu] = sb; hb[r][32 + uu] = sc;
      }
      *cp2 = cv;
    }
    __syncthreads();

    if (tid < 128) {   // assemble short8 h-limbs, emit in A-fragment layout
      int r = tid >> 1, s = tid & 1;
      int m = mb * 64 + r;
      int ubase = ub * 16 + s * 8;
      short8 h0 = *(const short8*)&hb[r][s * 8];
      short8 h1 = *(const short8*)&hb[r][16 + s * 8];
      short8 h2 = *(const short8*)&hb[r][32 + s * 8];
      int mtw = m >> 4, r16 = m & 15;
      int kcw = ubase >> 5, ko = ubase & 31;
      int lane_t = r16 + 16 * (ko >> 3);
      size_t base = ((size_t)(mtw * 32 + kcw) * 3) * 64 + lane_t;
      slotW[base] = h0; slotW[base + 64] = h1; slotW[base + 128] = h2;
      if (Hring)  // hi limb only, single-limb layout, for the projection
        Hring[(size_t)i * HR + (size_t)(mtw * 32 + kcw) * 64 + lane_t] = h0;
    }
    __syncthreads();   // drains vmcnt: h stores complete (at least to L2)

    if (i + 1 < SEG_STEPS) {   // last step: kernel-end release suffices
      if (tid == 0) {
        unsigned tick = (unsigned)(t + 1);     // monotonic over the whole run
        // RELEASE: wbl2 (publish h to LLC), NO acquire/inv anywhere -> W
        // stays resident in L2. Freshness of h reads is structural (ring).
        unsigned old = __hip_atomic_fetch_add(cnt, 1u, __ATOMIC_RELEASE,
                                              __HIP_MEMORY_SCOPE_AGENT);
        if (old == 63u) {            // last of the 64-block mb-group
          __hip_atomic_store(cnt, 0u, __ATOMIC_RELAXED,
                             __HIP_MEMORY_SCOPE_AGENT);
          __hip_atomic_store(gen, tick, __ATOMIC_RELEASE,
                             __HIP_MEMORY_SCOPE_AGENT);
        } else {
          while (__hip_atomic_load(gen, __ATOMIC_RELAXED,
                                   __HIP_MEMORY_SCOPE_AGENT) < tick)
            __builtin_amdgcn_s_sleep(2);
        }
      }
      __syncthreads();
      asm volatile("" ::: "memory");
    }
  }
}

// ---------------------------------------------------------------------------
// Fused projection: y = relu(hs @ d1W + b1) @ d2W + b2 over a 32-step chunk.
// 128 blocks x 256 thr; hs = hi-limb ring (single pass, bf16 error ~1e-3 ok).
// ---------------------------------------------------------------------------
__global__ __launch_bounds__(256) void proj(
    const short8* __restrict__ HS, const short8* __restrict__ W1,
    const float* __restrict__ b1, const short8* __restrict__ W2,
    const float* __restrict__ b2, float* __restrict__ out, int t0) {
  int tid = threadIdx.x;
  int lane = tid & 63, wv = tid >> 6;
  int wr = wv & 1, wc = wv >> 1;
  int tloc = blockIdx.x >> 2, mb = blockIdx.x & 3;
  int t = t0 + tloc;
  const short8* A = HS + (size_t)tloc * 16 * 32 * 64;
  int u16 = lane & 15, quad = lane >> 4;
  int mt0 = mb * 4 + wr * 2;
  __shared__ short a1f[4][8][512];   // A1 quarter in A-fragment layout, 32 KB
  const f32x4 z4 = {0.f, 0.f, 0.f, 0.f};
  f32x4 acc2[2][4];
#pragma unroll
  for (int i = 0; i < 2; ++i)
#pragma unroll
    for (int jj = 0; jj < 4; ++jj) acc2[i][jj] = z4;

  for (int q = 0; q < 4; ++q) {
    f32x4 acc1[2][8];
#pragma unroll
    for (int i = 0; i < 2; ++i)
#pragma unroll
      for (int n = 0; n < 8; ++n) acc1[i][n] = z4;
    for (int kc = 0; kc < 32; ++kc) {
      short8 av0 = A[(size_t)(mt0 * 32 + kc) * 64 + lane];
      short8 av1 = A[(size_t)((mt0 + 1) * 32 + kc) * 64 + lane];
#pragma unroll
      for (int n = 0; n < 8; ++n) {
        int nt = q * 16 + wc * 8 + n;
        short8 bv = W1[(size_t)(nt * 32 + kc) * 64 + lane];
        acc1[0][n] = MFMA(av0, bv, acc1[0][n]);
        acc1[1][n] = MFMA(av1, bv, acc1[1][n]);
      }
    }
    __syncthreads();   // previous quarter's GEMM2 reads are done
#pragma unroll
    for (int i = 0; i < 2; ++i)
#pragma unroll
      for (int n = 0; n < 8; ++n)
#pragma unroll
        for (int r = 0; r < 4; ++r) {
          int rl = wr * 32 + i * 16 + quad * 4 + r;
          int nloc = wc * 128 + n * 16 + u16;
          float v = fmaxf(acc1[i][n][r] + b1[q * 256 + nloc], 0.f);
          int mtl = rl >> 4, r16 = rl & 15;
          int kcl = nloc >> 5, ko = nloc & 31;
          a1f[mtl][kcl][(r16 + 16 * (ko >> 3)) * 8 + (ko & 7)] = f2bf(v);
        }
    __syncthreads();
    for (int kcl = 0; kcl < 8; ++kcl) {
      short8 av0 = *(const short8*)&a1f[wr * 2 + 0][kcl][lane * 8];
      short8 av1 = *(const short8*)&a1f[wr * 2 + 1][kcl][lane * 8];
#pragma unroll
      for (int jj = 0; jj < 4; ++jj) {
        int nt2 = wc * 4 + jj;
        short8 bv = W2[(size_t)(nt2 * 32 + q * 8 + kcl) * 64 + lane];
        acc2[0][jj] = MFMA(av0, bv, acc2[0][jj]);
        acc2[1][jj] = MFMA(av1, bv, acc2[1][jj]);
      }
    }
  }
#pragma unroll
  for (int i = 0; i < 2; ++i)
#pragma unroll
    for (int jj = 0; jj < 4; ++jj)
#pragma unroll
      for (int r = 0; r < 4; ++r) {
        int rl = wr * 32 + i * 16 + quad * 4 + r;
        int f = wc * 64 + jj * 16 + u16;
        int bb = mb * 64 + rl;
        out[((size_t)bb * 512 + t) * 128 + f] = acc2[i][jj][r] + b2[f];
      }
}

static void launch_seg(const void* fn, void** args, hipStream_t stream) {
  hipError_t e = hipLaunchCooperativeKernel(fn, dim3(256), dim3(512), args, 0,
                                            stream);
  if (e != hipSuccess) {
    // Fallback: plain launch. Grid == CU count at 1 block/CU -> co-resident.
    fprintf(stderr, "coop launch failed (%s); falling back to plain launch\n",
            hipGetErrorString(e));
    hipLaunchKernel(fn, dim3(256), dim3(512), args, 0, stream);
  }
}

extern "C" void kernel_launch(void* const* d_in, const int* in_sizes, int n_in,
                              void* d_out, int out_size, void* d_ws, size_t ws_size,
                              hipStream_t stream) {
  const float* x     = (const float*)d_in[0];
  const float* encWx = (const float*)d_in[1];
  const float* encWh = (const float*)d_in[2];
  const float* encb  = (const float*)d_in[3];
  const float* decWx = (const float*)d_in[4];
  const float* decWh = (const float*)d_in[5];
  const float* decb  = (const float*)d_in[6];
  const float* d1W   = (const float*)d_in[7];
  const float* d1b   = (const float*)d_in[8];
  const float* d2W   = (const float*)d_in[9];
  const float* d2b   = (const float*)d_in[10];

  char* ws = (char*)d_ws;
  size_t off = 0;
  short8* Wenc = (short8*)(ws + off); off += (size_t)256 * 36 * 3 * 64 * 16;  // 28.3 MB
  short8* Wdec = (short8*)(ws + off); off += (size_t)256 * 32 * 3 * 64 * 16;  // 25.2 MB
  short8* W1   = (short8*)(ws + off); off += (size_t)64 * 32 * 64 * 16;       //  2.10 MB
  short8* W2   = (short8*)(ws + off); off += (size_t)8 * 32 * 64 * 16;        //  0.26 MB
  short8* Xr   = (short8*)(ws + off); off += (size_t)32 * 16 * 4 * 3 * 64 * 16;        //  6.29 MB
  short8* ring = (short8*)(ws + off); off += (size_t)RING_SLOTS * 16 * 32 * 3 * 64 * 16; // 14.16 MB
  short8* Hring= (short8*)(ws + off); off += (size_t)32 * 16 * 32 * 64 * 16;           // 16.78 MB
  float*  cst  = (float*)(ws + off);  off += (size_t)256 * 1024 * 4;                   //  1.05 MB
  unsigned* bar = (unsigned*)(ws + off); off += 256;  // cnt[4] + gen[4]
  (void)in_sizes; (void)n_in; (void)out_size;  // total ~94.1 MB
  if (ws_size < off) {
    fprintf(stderr, "kernel_launch: ws_size=%zu < needed=%zu -- aborting launch\n",
            ws_size, off);
    return;
  }

  pack_w<<<2304, 256, 0, stream>>>(encWh, encWx, Wenc, 36, 1, 4096, 3);
  pack_w<<<2048, 256, 0, stream>>>(decWx, decWh, Wdec, 32, 0, 4096, 3);
  pack_w<<<512, 256, 0, stream>>>(d1W, nullptr, W1, 32, 2, 1024, 1);
  pack_w<<<64, 256, 0, stream>>>(d2W, nullptr, W2, 32, 3, 128, 1);
  zero_f<<<1536, 256, 0, stream>>>((float*)ring, 16 * 32 * 3 * 64 * 8);  // slot 0: h0 = 0
  zero_f<<<1024, 256, 0, stream>>>(cst, 256 * 1024);                     // c0 = 0
  zero_f<<<1, 256, 0, stream>>>((float*)bar, 8);                         // barrier state

  const size_t HR = (size_t)16 * 32 * 64;   // short8 per hi-limb h-state

  for (int c = 0; c < 16; ++c) {            // encoder: 16 chunks x 4 segs x 8 steps
    pack_x32<<<512, 256, 0, stream>>>(x, Xr, c * 32);
    for (int k = 0; k < 4; ++k) {
      const short8* axp = Xr; const short8* wp = Wenc; const float* bp = encb;
      float* cp = cst; short8* rp = ring; short8* hrp = nullptr;
      int gs = c * 32 + k * 8; unsigned* barp = bar;
      void* args[] = {&axp, &wp, &bp, &cp, &rp, &hrp, &gs, &barp};
      launch_seg((const void*)lstm_seg<36>, args, stream);
    }
  }
  for (int c = 0; c < 16; ++c) {            // decoder: 16 chunks x 4 segs x 8 steps
    for (int k = 0; k < 4; ++k) {
      const short8* axp = nullptr; const short8* wp = Wdec; const float* bp = decb;
      float* cp = cst; short8* rp = ring;
      short8* hrp = Hring + (size_t)(k * 8) * HR;
      int gs = 512 + c * 32 + k * 8; unsigned* barp = bar;
      void* args[] = {&axp, &wp, &bp, &cp, &rp, &hrp, &gs, &barp};
      launch_seg((const void*)lstm_seg<32>, args, stream);
    }
    proj<<<128, 256, 0, stream>>>(Hring, W1, d1b, W2, d2b, (float*)d_out, c * 32);
  }
}

// Round 3
// 38879.181 us; speedup vs baseline: 1.6247x; 1.1672x over previous
//
#include <hip/hip_runtime.h>
#include <hip/hip_bf16.h>
#include <math.h>
#include <stdio.h>

// EncoDecLSTM: B=256, T=512, F=128, U=1024.
// R6: persistent 32-step cooperative segments, W-resident-in-L2 design.
// R5 diagnosis: (1) one 31ms outlier dispatch from a barrier wedge -- cnt
// reset race + relaxed-load spin served stale from the non-coherent XCD L2;
// (2) still fetch-bound: 20.9 MB/step = whole W refetched because the
// 3-limb h-ring stream (1.57MB/step) evicted W (4.7MB > 4MB L2/XCD), and B
// loads were load->MFMA dependent (zero prefetch depth, 530 GB/s effective).
// This round:
//  (a) barrier: monotonic cnt (no reset race) + spin with fetch_add(gen,0)
//      fallback (RMW always reaches LLC -> never stale-wedges).
//  (b) fp32 h-ring with NON-TEMPORAL loads/stores (stream self-evicts, W
//      stays L2-hot); bf16 limbs produced on-the-fly by split3 at LDS
//      staging time -> bit-identical MFMA inputs.
//  (c) software-pipelined phases: per kc-pair {ds_write A(j+1); reg-load
//      A(j+2); reg-prefetch B(j+1)}; one raw s_barrier+lgkmcnt(0); 24 MFMA.
//      No vmcnt(0) drains in the main loop.
//  (d) SEG_STEPS=32 (ring 33 slots); Wdec packed after encoder into the
//      same buffer (workspace ~87 MB).
// GEMM product order and gate math bit-identical to R3/R4/R5 -> absmax must
// reproduce 0.0078125 exactly.
// Numerics: fp32-equivalent recurrence via 3-limb bf16 MFMA (hi/mid/lo = 24
// mantissa bits; limb products hh,hm,mh,mm,hl,lh, fp32 accumulate).
// Decoder identity: x_in == h, so z = h@(dec_Wx+dec_Wh)+b. Encoder folds
// x@Wx via K-concat (K=1152=36*32).

typedef __attribute__((ext_vector_type(8))) short short8;   // 8 x bf16
typedef __attribute__((ext_vector_type(4))) float f32x4;

#define MFMA(a, b, c) __builtin_amdgcn_mfma_f32_16x16x32_bf16(a, b, c, 0, 0, 0)

#define SEG_STEPS 32
#define RING_SLOTS 33   // SEG+1: every slot index read at exactly one step/launch
#define SLOT_F4 65536   // f32x4 per ring slot (256*1024 floats)

__device__ __forceinline__ short f2bf(float f) {
  union { __hip_bfloat16 h; short s; } u;
  u.h = __float2bfloat16(f);
  return u.s;
}
__device__ __forceinline__ void split3(float x, short& a, short& b, short& c) {
  union { __hip_bfloat16 h; short s; } u;
  u.h = __float2bfloat16(x); a = u.s;
  float r1 = x - __bfloat162float(u.h);
  u.h = __float2bfloat16(r1); b = u.s;
  float r2 = r1 - __bfloat162float(u.h);
  u.h = __float2bfloat16(r2); c = u.s;
}
__device__ __forceinline__ float sigm(float x) { return 1.0f / (1.0f + expf(-x)); }

__device__ __forceinline__ void split8(const f32x4& a, const f32x4& b,
                                       short8& v0, short8& v1, short8& v2) {
  float ff[8] = {a.x, a.y, a.z, a.w, b.x, b.y, b.z, b.w};
#pragma unroll
  for (int jj = 0; jj < 8; ++jj) {
    short sa, sb, sc; split3(ff[jj], sa, sb, sc);
    v0[jj] = sa; v1[jj] = sb; v2[jj] = sc;
  }
}

// ---------------------------------------------------------------------------
// Pack weight matrix into B-fragment layout, 1 or 3 limbs (unchanged).
// ---------------------------------------------------------------------------
__global__ void pack_w(const float* __restrict__ a, const float* __restrict__ b,
                       short8* __restrict__ dst, int KC, int mode, int ncols,
                       int limbs) {
  int gid = blockIdx.x * 256 + threadIdx.x;
  int lane = gid & 63;
  int kc = (gid >> 6) % KC;
  int nt = gid / (KC * 64);
  int u16 = lane & 15, kq = lane >> 4;
  int kbase = kc * 32 + kq * 8;
  int col;
  if (mode <= 1) { int g = nt & 3, ub = nt >> 2; col = g * 1024 + ub * 16 + u16; }
  else col = nt * 16 + u16;
  short8 v0, v1, v2;
#pragma unroll
  for (int j = 0; j < 8; ++j) {
    int k = kbase + j;
    float x;
    if (mode == 0)      x = a[(size_t)k * 4096 + col] + b[(size_t)k * 4096 + col];
    else if (mode == 1) x = (k < 1024) ? a[(size_t)k * 4096 + col]
                                       : b[(size_t)(k - 1024) * 4096 + col];
    else                x = a[(size_t)k * ncols + col];
    short sa, sb, sc; split3(x, sa, sb, sc);
    v0[j] = sa; v1[j] = sb; v2[j] = sc;
  }
  if (limbs == 3) {
    size_t base = (size_t)(nt * KC + kc) * 3 * 64 + lane;
    dst[base] = v0; dst[base + 64] = v1; dst[base + 128] = v2;
  } else {
    dst[(size_t)(nt * KC + kc) * 64 + lane] = v0;
  }
}

// Pack 32 timesteps of input x into fp32 A-fragment ring (pure relayout).
// dst f8-idx ((tloc*16+mt)*4+kx)*64+lane  holds x[b=mt*16+(lane&15)][t0+tloc]
// [f = kx*32+(lane>>4)*8 .. +7]
__global__ void pack_x32f(const float* __restrict__ src, f32x4* __restrict__ dst,
                          int t0) {
  int gid = blockIdx.x * 256 + threadIdx.x;
  int lane = gid & 63;
  int kx = (gid >> 6) & 3;
  int mt = (gid >> 8) & 15;
  int tloc = gid >> 12;            // 0..31
  int bb = mt * 16 + (lane & 15);
  int fb = kx * 32 + (lane >> 4) * 8;
  const float* s = src + ((size_t)bb * 512 + (t0 + tloc)) * 128 + fb;
  f32x4 a = *(const f32x4*)s;
  f32x4 b = *(const f32x4*)(s + 4);
  size_t base = ((size_t)((tloc * 16 + mt) * 4 + kx) * 64 + lane) * 2;
  dst[base] = a; dst[base + 1] = b;
}

__global__ void zero_f(float* p, int n) {
  int i = blockIdx.x * 256 + threadIdx.x;
  if (i < n) p[i] = 0.f;
}

// ---------------------------------------------------------------------------
// Persistent LSTM segment: SEG_STEPS timesteps per cooperative launch.
// 256 blocks x 512 thr (8 waves). Block owns 64 rows (mb) x 16 units (ub).
// Compute tile per wave: 32 rows x 16 gate-cols (wr=wv&1, wc=wv>>1).
// Staging role per wave: (wkcin=wv>>2, wmtl=wv&3); thread stages one
// (kc,mt,lane) float8 of h/x -> split3 -> 3 ds_write_b128.
// Pipeline per kc-pair phase: ds_write A(j+1) | reg-load A(j+2) (NT) |
// reg-prefetch B(j+1) from L2-hot W | lgkmcnt(0)+s_barrier | 24 MFMA.
// A: 3-buffer LDS ring (one barrier/phase is race-free: writer of phase
// j+1 targets (j+2)%3, slowest reader holds j%3).
// Inter-step: per-mb group of 64 blocks; monotonic cnt (64*tick target),
// RELEASE RMW publish (wbl2, no inv); spin = relaxed polls + fetch_add(gen,0)
// RMW fallback (always coherent). h ring slot = t % 33 -> fresh addresses.
// ---------------------------------------------------------------------------
template<int KCT>
__global__ __launch_bounds__(512) void lstm_seg(
    const f32x4* __restrict__ Xr4, const short8* __restrict__ W,
    const float* __restrict__ bias, float* __restrict__ cst,
    f32x4* __restrict__ ring4, short8* __restrict__ Hring,
    int gstep, unsigned* __restrict__ bar) {
  constexpr int NJ = KCT / 2;
  int tid = threadIdx.x;
  int lane = tid & 63, wv = tid >> 6;
  int wr = wv & 1, wc = wv >> 1;                 // compute: rows 2wr..2wr+1 (mt-local), gate wc
  int wkcin = wv >> 2, wmtl = wv & 3;            // staging role
  int xcd = blockIdx.x & 7, idx = blockIdx.x >> 3;
  int mb = idx & 3, ub = xcd * 8 + (idx >> 2);   // ub in [0,64)
  int u16 = lane & 15, quad = lane >> 4;
  int smt = mb * 4 + wmtl;                       // staging mt (global)
  const size_t HR = (size_t)16 * 32 * 64;        // short8 per hi-limb h-state

  __shared__ short8 Abuf[3][2][4][3][64];        // 72 KB A-limb ring
  __shared__ float zt[64][68];                   // 17.4 KB gate pre-activations
  __shared__ __align__(16) float hbf[64][20];    // 5 KB new-h bounce

  float bv = bias[wc * 1024 + ub * 16 + u16];
  unsigned* cnt = bar + mb;
  unsigned* gen = bar + 4 + mb;
  unsigned ebase = (unsigned)(gstep >> 5) * 31u; // events before this launch
  const short8* Wb = W + ((size_t)(ub * 4 + wc) * KCT) * 3 * 64 + lane;

#define LOADB(P, B00, B01, B02, B10, B11, B12) do {                     \
    const short8* bq_ = Wb + (size_t)(P) * 384;                         \
    B00 = bq_[0];   B01 = bq_[64];  B02 = bq_[128];                     \
    B10 = bq_[192]; B11 = bq_[256]; B12 = bq_[320]; } while (0)

#define LOADRA(P) do {                                                  \
    int kc0_ = 2 * (P) + wkcin;                                         \
    const f32x4* sp_;                                                   \
    if (KCT == 36 && kc0_ >= 32)                                        \
      sp_ = Xr4 + ((((size_t)(t & 31) * 16 + smt) * 4 + (kc0_ - 32)) * 64 + lane) * 2; \
    else                                                                \
      sp_ = ringR4 + (((size_t)(smt * 32 + kc0_)) * 64 + lane) * 2;     \
    rA0 = __builtin_nontemporal_load(sp_);                              \
    rA1 = __builtin_nontemporal_load(sp_ + 1); } while (0)

#define WRITEA(BW) do {                                                 \
    short8 v0_, v1_, v2_;                                               \
    split8(rA0, rA1, v0_, v1_, v2_);                                    \
    short8* d_ = &Abuf[BW][wkcin][wmtl][0][lane];                       \
    d_[0] = v0_; d_[64] = v1_; d_[128] = v2_; } while (0)

#define BARSYNC() do {                                                  \
    asm volatile("s_waitcnt lgkmcnt(0)" ::: "memory");                  \
    __builtin_amdgcn_s_barrier();                                       \
    asm volatile("" ::: "memory"); } while (0)

  // limb products hh,hm,mh,mm,hl,lh -- same per-acc order as R3/R4/R5
#define COMPUTE(BJ, B00, B01, B02, B10, B11, B12) do {                  \
    short8 x0 = Abuf[BJ][0][2 * wr + 0][0][lane];                       \
    short8 x1 = Abuf[BJ][0][2 * wr + 0][1][lane];                       \
    short8 x2 = Abuf[BJ][0][2 * wr + 0][2][lane];                       \
    short8 y0 = Abuf[BJ][0][2 * wr + 1][0][lane];                       \
    short8 y1 = Abuf[BJ][0][2 * wr + 1][1][lane];                       \
    short8 y2 = Abuf[BJ][0][2 * wr + 1][2][lane];                       \
    acc0 = MFMA(x0, B00, acc0);  acc1 = MFMA(y0, B00, acc1);            \
    acc0 = MFMA(x0, B01, acc0);  acc1 = MFMA(y0, B01, acc1);            \
    acc0 = MFMA(x1, B00, acc0);  acc1 = MFMA(y1, B00, acc1);            \
    acc0 = MFMA(x1, B01, acc0);  acc1 = MFMA(y1, B01, acc1);            \
    acc0 = MFMA(x0, B02, acc0);  acc1 = MFMA(y0, B02, acc1);            \
    acc0 = MFMA(x2, B00, acc0);  acc1 = MFMA(y2, B00, acc1);            \
    x0 = Abuf[BJ][1][2 * wr + 0][0][lane];                              \
    x1 = Abuf[BJ][1][2 * wr + 0][1][lane];                              \
    x2 = Abuf[BJ][1][2 * wr + 0][2][lane];                              \
    y0 = Abuf[BJ][1][2 * wr + 1][0][lane];                              \
    y1 = Abuf[BJ][1][2 * wr + 1][1][lane];                              \
    y2 = Abuf[BJ][1][2 * wr + 1][2][lane];                              \
    acc0 = MFMA(x0, B10, acc0);  acc1 = MFMA(y0, B10, acc1);            \
    acc0 = MFMA(x0, B11, acc0);  acc1 = MFMA(y0, B11, acc1);            \
    acc0 = MFMA(x1, B10, acc0);  acc1 = MFMA(y1, B10, acc1);            \
    acc0 = MFMA(x1, B11, acc0);  acc1 = MFMA(y1, B11, acc1);            \
    acc0 = MFMA(x0, B12, acc0);  acc1 = MFMA(y0, B12, acc1);            \
    acc0 = MFMA(x2, B10, acc0);  acc1 = MFMA(y2, B10, acc1); } while (0)

  for (int i = 0; i < SEG_STEPS; ++i) {
    int t = gstep + i;
    const f32x4* ringR4 = ring4 + (size_t)(t % RING_SLOTS) * SLOT_F4;
    f32x4* ringW4 = ring4 + (size_t)((t + 1) % RING_SLOTS) * SLOT_F4;
    const f32x4 zf4 = {0.f, 0.f, 0.f, 0.f};
    f32x4 acc0 = {0.f, 0.f, 0.f, 0.f}, acc1 = {0.f, 0.f, 0.f, 0.f};
    (void)zf4;
    f32x4 rA0, rA1;
    short8 p00, p01, p02, p10, p11, p12;   // B set0
    short8 q00, q01, q02, q10, q11, q12;   // B set1

    // prologue: A pair0 -> Abuf[0]; rA <- pair1; B pair0 -> set0
    LOADRA(0);
    LOADB(0, p00, p01, p02, p10, p11, p12);
    WRITEA(0);
    LOADRA(1);

    for (int m2 = 0; m2 < NJ / 2; ++m2) {
      int j0 = 2 * m2, j1 = 2 * m2 + 1;
      // ---- phase j0: stage pair j0+1, prefetch B j1, compute pair j0 ----
      WRITEA((j0 + 1) % 3);
      if (m2 < NJ / 2 - 1) LOADRA(j0 + 2);
      LOADB(j0 + 1, q00, q01, q02, q10, q11, q12);
      BARSYNC();
      COMPUTE(j0 % 3, p00, p01, p02, p10, p11, p12);
      // ---- phase j1 ----
      if (m2 < NJ / 2 - 1) {
        WRITEA((j1 + 1) % 3);
        LOADRA(j1 + 2);
        LOADB(j1 + 1, p00, p01, p02, p10, p11, p12);
      }
      BARSYNC();
      COMPUTE(j1 % 3, q00, q01, q02, q10, q11, q12);
    }

    // C/D layout: col = lane&15, row = quad*4 + reg   (m89/m91-verified)
#pragma unroll
    for (int r = 0; r < 4; ++r) {
      zt[(2 * wr + 0) * 16 + quad * 4 + r][wc * 16 + u16] = acc0[r] + bv;
      zt[(2 * wr + 1) * 16 + quad * 4 + r][wc * 16 + u16] = acc1[r] + bv;
    }
    __syncthreads();

    // gates: all 512 threads, 2 units each (bit-identical math)
    {
      int r = tid >> 3, up = tid & 7;
      int m = mb * 64 + r;
      float2* cp2 = (float2*)(cst + (size_t)m * 1024 + ub * 16) + up;
      float2 cv = *cp2;
#pragma unroll
      for (int jj = 0; jj < 2; ++jj) {
        int uu = up * 2 + jj;
        float iv = zt[r][uu];
        float fv = zt[r][16 + uu];
        float gv = zt[r][32 + uu];
        float ov = zt[r][48 + uu];
        float cin = jj ? cv.y : cv.x;
        float cn = sigm(fv) * cin + sigm(iv) * tanhf(gv);
        if (jj) cv.y = cn; else cv.x = cn;
        hbf[r][uu] = sigm(ov) * tanhf(cn);
      }
      *cp2 = cv;
    }
    __syncthreads();

    if (tid < 128) {   // emit fp32 h (NT) + hi-limb bf16 for projection
      int r = tid >> 1, s = tid & 1;
      int m = mb * 64 + r;
      int ubase = ub * 16 + s * 8;
      const float* hp = &hbf[r][s * 8];
      f32x4 h4a = *(const f32x4*)hp;
      f32x4 h4b = *(const f32x4*)(hp + 4);
      int mtw = m >> 4, r16 = m & 15;
      int kcw = ubase >> 5, ko = ubase & 31;
      int lane_t = r16 + 16 * (ko >> 3);
      size_t idx = ((size_t)(mtw * 32 + kcw) * 64 + lane_t);
      __builtin_nontemporal_store(h4a, ringW4 + idx * 2);
      __builtin_nontemporal_store(h4b, ringW4 + idx * 2 + 1);
      if (Hring) {
        short8 h0;
#pragma unroll
        for (int jj = 0; jj < 8; ++jj) h0[jj] = f2bf(hp[jj]);
        __builtin_nontemporal_store(h0, Hring + (size_t)i * HR + idx);
      }
    }

    if (i + 1 < SEG_STEPS) {           // last step: kernel-end release suffices
      __syncthreads();                 // drain all h stores (vmcnt 0)
      if (tid == 0) {
        unsigned tick = ebase + (unsigned)i + 1u;   // monotonic over whole run
        unsigned old = __hip_atomic_fetch_add(cnt, 1u, __ATOMIC_RELEASE,
                                              __HIP_MEMORY_SCOPE_AGENT);
        if (old == 64u * tick - 1u) {  // 64th arriver of this event
          __hip_atomic_store(gen, tick, __ATOMIC_RELEASE,
                             __HIP_MEMORY_SCOPE_AGENT);
        } else {
          unsigned v = 0;
          do {
            for (int ph = 0; ph < 8; ++ph) {
              v = __hip_atomic_load(gen, __ATOMIC_RELAXED,
                                    __HIP_MEMORY_SCOPE_AGENT);
              if (v >= tick) break;
              __builtin_amdgcn_s_sleep(1);
            }
            if (v < tick)   // RMW: guaranteed coherent read (no stale-L2 wedge)
              v = __hip_atomic_fetch_add(gen, 0u, __ATOMIC_RELAXED,
                                         __HIP_MEMORY_SCOPE_AGENT);
          } while (v < tick);
        }
      }
      __syncthreads();
    }
  }
#undef LOADB
#undef LOADRA
#undef WRITEA
#undef BARSYNC
#undef COMPUTE
}

// ---------------------------------------------------------------------------
// Fused projection: y = relu(hs @ d1W + b1) @ d2W + b2 over a 32-step chunk.
// 128 blocks x 256 thr; hs = hi-limb ring (single pass, bf16 error ~1e-3 ok).
// ---------------------------------------------------------------------------
__global__ __launch_bounds__(256) void proj(
    const short8* __restrict__ HS, const short8* __restrict__ W1,
    const float* __restrict__ b1, const short8* __restrict__ W2,
    const float* __restrict__ b2, float* __restrict__ out, int t0) {
  int tid = threadIdx.x;
  int lane = tid & 63, wv = tid >> 6;
  int wr = wv & 1, wc = wv >> 1;
  int tloc = blockIdx.x >> 2, mb = blockIdx.x & 3;
  int t = t0 + tloc;
  const short8* A = HS + (size_t)tloc * 16 * 32 * 64;
  int u16 = lane & 15, quad = lane >> 4;
  int mt0 = mb * 4 + wr * 2;
  __shared__ short a1f[4][8][512];   // A1 quarter in A-fragment layout, 32 KB
  const f32x4 z4 = {0.f, 0.f, 0.f, 0.f};
  f32x4 acc2[2][4];
#pragma unroll
  for (int i = 0; i < 2; ++i)
#pragma unroll
    for (int jj = 0; jj < 4; ++jj) acc2[i][jj] = z4;

  for (int q = 0; q < 4; ++q) {
    f32x4 acc1[2][8];
#pragma unroll
    for (int i = 0; i < 2; ++i)
#pragma unroll
      for (int n = 0; n < 8; ++n) acc1[i][n] = z4;
    for (int kc = 0; kc < 32; ++kc) {
      short8 av0 = A[(size_t)(mt0 * 32 + kc) * 64 + lane];
      short8 av1 = A[(size_t)((mt0 + 1) * 32 + kc) * 64 + lane];
#pragma unroll
      for (int n = 0; n < 8; ++n) {
        int nt = q * 16 + wc * 8 + n;
        short8 bv = W1[(size_t)(nt * 32 + kc) * 64 + lane];
        acc1[0][n] = MFMA(av0, bv, acc1[0][n]);
        acc1[1][n] = MFMA(av1, bv, acc1[1][n]);
      }
    }
    __syncthreads();   // previous quarter's GEMM2 reads are done
#pragma unroll
    for (int i = 0; i < 2; ++i)
#pragma unroll
      for (int n = 0; n < 8; ++n)
#pragma unroll
        for (int r = 0; r < 4; ++r) {
          int rl = wr * 32 + i * 16 + quad * 4 + r;
          int nloc = wc * 128 + n * 16 + u16;
          float v = fmaxf(acc1[i][n][r] + b1[q * 256 + nloc], 0.f);
          int mtl = rl >> 4, r16 = rl & 15;
          int kcl = nloc >> 5, ko = nloc & 31;
          a1f[mtl][kcl][(r16 + 16 * (ko >> 3)) * 8 + (ko & 7)] = f2bf(v);
        }
    __syncthreads();
    for (int kcl = 0; kcl < 8; ++kcl) {
      short8 av0 = *(const short8*)&a1f[wr * 2 + 0][kcl][lane * 8];
      short8 av1 = *(const short8*)&a1f[wr * 2 + 1][kcl][lane * 8];
#pragma unroll
      for (int jj = 0; jj < 4; ++jj) {
        int nt2 = wc * 4 + jj;
        short8 bv = W2[(size_t)(nt2 * 32 + q * 8 + kcl) * 64 + lane];
        acc2[0][jj] = MFMA(av0, bv, acc2[0][jj]);
        acc2[1][jj] = MFMA(av1, bv, acc2[1][jj]);
      }
    }
  }
#pragma unroll
  for (int i = 0; i < 2; ++i)
#pragma unroll
    for (int jj = 0; jj < 4; ++jj)
#pragma unroll
      for (int r = 0; r < 4; ++r) {
        int rl = wr * 32 + i * 16 + quad * 4 + r;
        int f = wc * 64 + jj * 16 + u16;
        int bb = mb * 64 + rl;
        out[((size_t)bb * 512 + t) * 128 + f] = acc2[i][jj][r] + b2[f];
      }
}

static void launch_seg(const void* fn, void** args, hipStream_t stream) {
  hipError_t e = hipLaunchCooperativeKernel(fn, dim3(256), dim3(512), args, 0,
                                            stream);
  if (e != hipSuccess) {
    // Fallback: plain launch. Grid == CU count at 1 block/CU -> co-resident.
    fprintf(stderr, "coop launch failed (%s); falling back to plain launch\n",
            hipGetErrorString(e));
    hipLaunchKernel(fn, dim3(256), dim3(512), args, 0, stream);
  }
}

extern "C" void kernel_launch(void* const* d_in, const int* in_sizes, int n_in,
                              void* d_out, int out_size, void* d_ws, size_t ws_size,
                              hipStream_t stream) {
  const float* x     = (const float*)d_in[0];
  const float* encWx = (const float*)d_in[1];
  const float* encWh = (const float*)d_in[2];
  const float* encb  = (const float*)d_in[3];
  const float* decWx = (const float*)d_in[4];
  const float* decWh = (const float*)d_in[5];
  const float* decb  = (const float*)d_in[6];
  const float* d1W   = (const float*)d_in[7];
  const float* d1b   = (const float*)d_in[8];
  const float* d2W   = (const float*)d_in[9];
  const float* d2b   = (const float*)d_in[10];

  char* ws = (char*)d_ws;
  size_t off = 0;
  short8* Wrec = (short8*)(ws + off); off += (size_t)256 * 36 * 3 * 64 * 16;  // 28.3 MB (enc, then dec)
  short8* W1   = (short8*)(ws + off); off += (size_t)64 * 32 * 64 * 16;       //  2.10 MB
  short8* W2   = (short8*)(ws + off); off += (size_t)8 * 32 * 64 * 16;        //  0.26 MB
  f32x4*  Xr   = (f32x4*)(ws + off);  off += (size_t)32 * 16 * 4 * 64 * 32;   //  4.19 MB
  f32x4*  ring = (f32x4*)(ws + off);  off += (size_t)RING_SLOTS * SLOT_F4 * 16; // 34.6 MB
  short8* Hring= (short8*)(ws + off); off += (size_t)32 * 16 * 32 * 64 * 16;  // 16.78 MB
  float*  cst  = (float*)(ws + off);  off += (size_t)256 * 1024 * 4;          //  1.05 MB
  unsigned* bar = (unsigned*)(ws + off); off += 256;  // cnt[4] + gen[4]
  (void)in_sizes; (void)n_in; (void)out_size;  // total ~87.3 MB
  if (ws_size < off) {
    fprintf(stderr, "kernel_launch: ws_size=%zu < needed=%zu -- aborting launch\n",
            ws_size, off);
    return;
  }

  pack_w<<<2304, 256, 0, stream>>>(encWh, encWx, Wrec, 36, 1, 4096, 3);
  pack_w<<<512, 256, 0, stream>>>(d1W, nullptr, W1, 32, 2, 1024, 1);
  pack_w<<<64, 256, 0, stream>>>(d2W, nullptr, W2, 32, 3, 128, 1);
  zero_f<<<1024, 256, 0, stream>>>((float*)ring, 256 * 1024);   // slot 0: h0 = 0
  zero_f<<<1024, 256, 0, stream>>>(cst, 256 * 1024);            // c0 = 0
  zero_f<<<1, 256, 0, stream>>>((float*)bar, 8);                // barrier state

  const size_t HR = (size_t)16 * 32 * 64;   // short8 per hi-limb h-state

  for (int c = 0; c < 16; ++c) {            // encoder: 16 segments x 32 steps
    pack_x32f<<<512, 256, 0, stream>>>(x, Xr, c * 32);
    const f32x4* axp = Xr; const short8* wp = Wrec; const float* bp = encb;
    float* cp = cst; f32x4* rp = ring; short8* hrp = nullptr;
    int gs = c * 32; unsigned* barp = bar;
    void* args[] = {&axp, &wp, &bp, &cp, &rp, &hrp, &gs, &barp};
    launch_seg((const void*)lstm_seg<36>, args, stream);
  }
  // repack W for the decoder into the same buffer (stream-ordered)
  pack_w<<<2048, 256, 0, stream>>>(decWx, decWh, Wrec, 32, 0, 4096, 3);
  for (int c = 0; c < 16; ++c) {            // decoder: 16 segments x 32 steps
    const f32x4* axp = nullptr; const short8* wp = Wrec; const float* bp = decb;
    float* cp = cst; f32x4* rp = ring; short8* hrp = Hring;
    int gs = 512 + c * 32; unsigned* barp = bar;
    void* args[] = {&axp, &wp, &bp, &cp, &rp, &hrp, &gs, &barp};
    launch_seg((const void*)lstm_seg<32>, args, stream);
    proj<<<128, 256, 0, stream>>>(Hring, W1, d1b, W2, d2b, (float*)d_out, c * 32);
  }
}